// Round 2
// baseline (1269.800 us; speedup 1.0000x reference)
//
#include <hip/hip_runtime.h>

typedef float v4f __attribute__((ext_vector_type(4)));

static constexpr float EPS = 1e-6f;

// DPP-based partial sum step: x += dpp_move(x); masked/out-of-bounds lanes add 0.
#define DPP_ADD(x, ctrl, rmask)                                               \
  x += __builtin_bit_cast(float, __builtin_amdgcn_update_dpp(                 \
           0, __builtin_bit_cast(int, x), ctrl, rmask, 0xf, true))

// Classic GCN full-wave64 sum: after this, lane 63 holds the total.
// row_shr:1,2,4,8 then row_bcast:15 (rows 1,3) and row_bcast:31 (rows 2,3).
#define WAVE_RED3(a, b, c)                                                    \
  do {                                                                        \
    DPP_ADD(a, 0x111, 0xf); DPP_ADD(b, 0x111, 0xf); DPP_ADD(c, 0x111, 0xf);   \
    DPP_ADD(a, 0x112, 0xf); DPP_ADD(b, 0x112, 0xf); DPP_ADD(c, 0x112, 0xf);   \
    DPP_ADD(a, 0x114, 0xf); DPP_ADD(b, 0x114, 0xf); DPP_ADD(c, 0x114, 0xf);   \
    DPP_ADD(a, 0x118, 0xf); DPP_ADD(b, 0x118, 0xf); DPP_ADD(c, 0x118, 0xf);   \
    DPP_ADD(a, 0x142, 0xa); DPP_ADD(b, 0x142, 0xa); DPP_ADD(c, 0x142, 0xa);   \
    DPP_ADD(a, 0x143, 0xc); DPP_ADD(b, 0x143, 0xc); DPP_ADD(c, 0x143, 0xc);   \
  } while (0)

__device__ __forceinline__ float bcast_lane63(float x) {
  return __builtin_bit_cast(
      float, __builtin_amdgcn_readlane(__builtin_bit_cast(int, x), 63));
}

// One block = one 64-lane wave = one batch chain. Lane i owns row i of M.
__global__ __launch_bounds__(64, 1)
void delta_mem_seq(const float* __restrict__ h,
                   const float* __restrict__ W,
                   const float* __restrict__ bias,
                   float* __restrict__ out,
                   int L) {
  const int b = blockIdx.x;
  const int lane = threadIdx.x;
  __shared__ float kring[8][64];   // async-load ring, 5 in flight
  __shared__ float rbuf[64];
  const float* __restrict__ hb = h + (size_t)b * (size_t)L * 64;
  const int LM1 = L - 1;

  v4f m4[16];
#pragma unroll
  for (int q = 0; q < 16; ++q) m4[q] = v4f{0.f, 0.f, 0.f, 0.f};

  // Prologue: issue k_0..k_4 into the ring (direct-to-LDS, lane i -> base+4i).
#pragma unroll
  for (int i = 0; i < 5; ++i) {
    int idx = (i < LM1 + 1) ? i : LM1;
    __builtin_amdgcn_global_load_lds(
        (const __attribute__((address_space(1))) void*)(hb + (size_t)idx * 64 + lane),
        (__attribute__((address_space(3))) void*)&kring[i][0], 4, 0, 0);
  }
  asm volatile("s_waitcnt vmcnt(4)" ::: "memory");  // buf0 (k_0) landed

  float ks0 = kring[0][lane];
  v4f kbA[16], kbB[16];
  {
    const v4f* kv = (const v4f*)&kring[0][0];
#pragma unroll
    for (int q = 0; q < 16; ++q) kbA[q] = kv[q];
  }
  float s2;
  {
    float t0 = ks0 * ks0, d1 = t0, d2 = t0;
    WAVE_RED3(t0, d1, d2);
    s2 = bcast_lane63(t0);
  }
  float r = 1.0f / (s2 + EPS);
  float vp = 0.f;  // M_0 k_0 = 0

  // Iter t: gate-step with k_t; produces vp = M_{t+1} k_{t+1}.
  auto body = [&](v4f* kbc, v4f* kbn, int t) {
    // issue k_{t+5} into ring slot (t+5)&7 (clamped index keeps vmcnt static)
    int idx = t + 5;
    if (idx > LM1) idx = LM1;
    __builtin_amdgcn_global_load_lds(
        (const __attribute__((address_space(1))) void*)(hb + (size_t)idx * 64 + lane),
        (__attribute__((address_space(3))) void*)&kring[(t + 5) & 7][0], 4, 0, 0);
    asm volatile("s_waitcnt vmcnt(4)" ::: "memory");  // k_{t+1} landed

    const float* kb = &kring[(t + 1) & 7][0];
    float ks1 = kb[lane];
    const v4f* kv = (const v4f*)kb;
#pragma unroll
    for (int q = 0; q < 16; ++q) kbn[q] = kv[q];

    // per-lane delta-rule quantities (critical path starts here)
    float u = fmaf(-vp, r, ks0);               // u = k_t - vp/denom
    float z = u * fmaf(s2, u, 2.0f * vp);      // 2*u*vp + s2*u^2 (gate summand)
    float cp = ks0 * ks1;                      // -> c = k_t . k_{t+1}
    float sp = ks1 * ks1;                      // -> s2_{t+1}

    // a = M_t . k_{t+1}  (independent of the gate; fills reduction latency)
    v4f ac0 = v4f{0.f, 0.f, 0.f, 0.f}, ac1 = ac0, ac2 = ac0, ac3 = ac0;
#pragma unroll
    for (int q = 0; q < 4; ++q) {
      ac0 = __builtin_elementwise_fma(m4[4 * q + 0], kbn[4 * q + 0], ac0);
      ac1 = __builtin_elementwise_fma(m4[4 * q + 1], kbn[4 * q + 1], ac1);
      ac2 = __builtin_elementwise_fma(m4[4 * q + 2], kbn[4 * q + 2], ac2);
      ac3 = __builtin_elementwise_fma(m4[4 * q + 3], kbn[4 * q + 3], ac3);
    }
    v4f acs = (ac0 + ac1) + (ac2 + ac3);
    float a = (acs.x + acs.y) + (acs.z + acs.w);

    WAVE_RED3(z, cp, sp);
    float zt  = bcast_lane63(z);
    float c   = bcast_lane63(cp);
    float s2n = bcast_lane63(sp);

    float rn = 1.0f / (s2n + EPS);             // next step's 1/denom (off-path)
    float gu = (zt > 0.f) ? u : 0.f;           // Hopfield gate

    // M += gu * k_t^T   (kbc = broadcast k_t)
    v4f guv = {gu, gu, gu, gu};
#pragma unroll
    for (int q = 0; q < 16; ++q)
      m4[q] = __builtin_elementwise_fma(guv, kbc[q], m4[q]);

    vp = fmaf(gu, c, a);                       // M_{t+1} k_{t+1}
    s2 = s2n;
    r = rn;
    ks0 = ks1;
  };

  int t = 0;
  for (; t + 1 < LM1; t += 2) {   // ping-pong broadcast buffers
    body(kbA, kbB, t);
    body(kbB, kbA, t + 1);
  }
  if (t < LM1) body(kbA, kbB, t);

  // vp now IS read = M_final @ h[:,L-1]
  rbuf[lane] = vp;
  __syncthreads();

  // out[b][o] = sum_i W[o][i]*read[i] + bias[o]
  const v4f* wv = (const v4f*)(W + lane * 64);
  const v4f* rv = (const v4f*)rbuf;
  v4f acc = v4f{0.f, 0.f, 0.f, 0.f};
#pragma unroll
  for (int q = 0; q < 16; ++q)
    acc = __builtin_elementwise_fma(wv[q], rv[q], acc);
  out[(size_t)b * 64 + lane] =
      bias[lane] + ((acc.x + acc.y) + (acc.z + acc.w));
}

extern "C" void kernel_launch(void* const* d_in, const int* in_sizes, int n_in,
                              void* d_out, int out_size, void* d_ws, size_t ws_size,
                              hipStream_t stream) {
  const float* h    = (const float*)d_in[0];
  const float* W    = (const float*)d_in[1];
  const float* bias = (const float*)d_in[2];
  float* out = (float*)d_out;

  const int H = in_sizes[2];            // 64
  const int B = out_size / H;           // 256
  const int L = in_sizes[0] / (B * H);  // 2048

  delta_mem_seq<<<B, 64, 0, stream>>>(h, W, bias, out, L);
}